// Round 2
// baseline (467.128 us; speedup 1.0000x reference)
//
#include <hip/hip_runtime.h>

// y[b,c,h,w] = x[b,c,h,w] * gamma[c] + beta[c]
// x: (8, 128, 256, 256) fp32. HW plane = 65536 elements -> 16384 float4s per channel.
// Grid-stride version: 2048 blocks x 256 threads = 524288 threads; n4 = 16777216
// -> exactly 32 float4 iterations per thread, zero tail.
// c = (i4 >> 14) & 127 is wave-uniform except at 16K boundaries (harmless).
// Stores are non-temporal (native ext_vector_type for the builtin): y is
// write-only, never re-read; keeps the output stream from evicting x, which
// (256 MiB) can sit entirely in the 256 MiB L3.

#define C_SHIFT4 14      // log2(256*256) - log2(4)
#define C_MASK   127     // NUM_FEATURE - 1

typedef float floatx4 __attribute__((ext_vector_type(4)));

__global__ __launch_bounds__(256) void scale_kernel(
    const floatx4* __restrict__ x4,
    const float* __restrict__ gamma,
    const float* __restrict__ beta,
    floatx4* __restrict__ y4,
    const long long n4)
{
    const long long stride = (long long)gridDim.x * blockDim.x;
    long long i4 = (long long)blockIdx.x * blockDim.x + threadIdx.x;

    #pragma unroll 4
    for (; i4 < n4; i4 += stride) {
        const int c = (int)((i4 >> C_SHIFT4) & C_MASK);
        const float g = gamma[c];
        const float b = beta[c];

        floatx4 v = x4[i4];
        v.x = fmaf(v.x, g, b);
        v.y = fmaf(v.y, g, b);
        v.z = fmaf(v.z, g, b);
        v.w = fmaf(v.w, g, b);
        __builtin_nontemporal_store(v, &y4[i4]);
    }
}

extern "C" void kernel_launch(void* const* d_in, const int* in_sizes, int n_in,
                              void* d_out, int out_size, void* d_ws, size_t ws_size,
                              hipStream_t stream) {
    const float* x     = (const float*)d_in[0];
    const float* gamma = (const float*)d_in[1];
    const float* beta  = (const float*)d_in[2];
    float* y           = (float*)d_out;

    const long long n  = (long long)out_size;   // 8*128*256*256 = 67108864 floats
    const long long n4 = n >> 2;                // 16777216 float4s

    const int block = 256;
    const int grid  = 2048;   // 8 blocks/CU x 256 CUs -> full 32-wave occupancy

    scale_kernel<<<dim3(grid), dim3(block), 0, stream>>>(
        (const floatx4*)x, gamma, beta, (floatx4*)y, n4);
}

// Round 4
// 460.601 us; speedup vs baseline: 1.0142x; 1.0142x over previous
//
#include <hip/hip_runtime.h>

// y[b,c,h,w] = x[b,c,h,w] * gamma[c] + beta[c]
// x: (8, 128, 256, 256) fp32. 65536 elements -> 16384 float4s per channel.
//
// Grid-stride: 2048 blocks x 256 threads = 524288 threads; n4 = 16777216
// -> exactly 32 float4 iterations per thread, zero tail.
//
// Channel hoist: stride = 524288 float4s = EXACTLY 32 channels, so a thread's
// channel sequence is (c0 + 32k) & 127 with period 4. Precompute the 4
// (gamma, beta) pairs once; inner loop is pure load -> 4 fma -> store.
//
// Stores are PLAIN (round-2 post-mortem: `nt` no-allocate stores bypassed the
// L2 write-combining path and capped writes at ~2 TB/s; the harness fills hit
// 6.5 TB/s with normal stores).

#define C_SHIFT4 14      // log2(16384 float4s per channel)
#define C_MASK   127     // NUM_FEATURE - 1

typedef float floatx4 __attribute__((ext_vector_type(4)));

__global__ __launch_bounds__(256) void scale_kernel(
    const floatx4* __restrict__ x4,
    const float* __restrict__ gamma,
    const float* __restrict__ beta,
    floatx4* __restrict__ y4,
    const long long n4)
{
    const long long stride = (long long)gridDim.x * blockDim.x;   // 524288
    const long long base   = (long long)blockIdx.x * blockDim.x + threadIdx.x;

    // Period-4 channel pattern (requires stride == 32 channels; grid=2048,block=256).
    float g[4], b[4];
    #pragma unroll
    for (int k = 0; k < 4; ++k) {
        const int c = (int)(((base + (long long)k * stride) >> C_SHIFT4) & C_MASK);
        g[k] = gamma[c];
        b[k] = beta[c];
    }

    #pragma unroll 1
    for (long long i4 = base; i4 < n4; i4 += 4 * stride) {
        #pragma unroll
        for (int k = 0; k < 4; ++k) {
            const long long j = i4 + (long long)k * stride;
            floatx4 v = x4[j];
            v.x = fmaf(v.x, g[k], b[k]);
            v.y = fmaf(v.y, g[k], b[k]);
            v.z = fmaf(v.z, g[k], b[k]);
            v.w = fmaf(v.w, g[k], b[k]);
            y4[j] = v;
        }
    }
}

extern "C" void kernel_launch(void* const* d_in, const int* in_sizes, int n_in,
                              void* d_out, int out_size, void* d_ws, size_t ws_size,
                              hipStream_t stream) {
    const float* x     = (const float*)d_in[0];
    const float* gamma = (const float*)d_in[1];
    const float* beta  = (const float*)d_in[2];
    float* y           = (float*)d_out;

    const long long n  = (long long)out_size;   // 67108864 floats
    const long long n4 = n >> 2;                // 16777216 float4s

    const int block = 256;
    const int grid  = 2048;   // stride math above assumes grid*block = 524288

    scale_kernel<<<dim3(grid), dim3(block), 0, stream>>>(
        (const floatx4*)x, gamma, beta, (floatx4*)y, n4);
}

// Round 5
// 424.850 us; speedup vs baseline: 1.0995x; 1.0841x over previous
//
#include <hip/hip_runtime.h>

// y[b,c,h,w] = x[b,c,h,w] * gamma[c] + beta[c]
// x: (8, 128, 256, 256) fp32. 65536 elements = 16384 float4s per channel.
//
// Round-4 post-mortem: grid-stride (8 MiB stride) lost ~45 us vs the dense
// one-pass mapping even with plain stores (fill-time calibration rules out
// session noise). Revert to dense mapping; refine R0 minimally:
//   - 2 float4s per thread, block-interleaved at blockDim stride
//     (j = bid*512 + k*256 + tid): per-instruction wave access stays a
//     contiguous 1 KiB line, each block covers a contiguous 8 KiB,
//     2 loads in flight per thread, half the blocks of R0.
//   - plain stores (R2: nt stores capped writes at ~2 TB/s).
// c = (j >> 14) & 127, wave-uniform within a 16 KiB-aligned span.

#define C_SHIFT4 14      // log2(16384 float4s per channel)
#define C_MASK   127     // NUM_FEATURE - 1

typedef float floatx4 __attribute__((ext_vector_type(4)));

__global__ __launch_bounds__(256) void scale_kernel(
    const floatx4* __restrict__ x4,
    const float* __restrict__ gamma,
    const float* __restrict__ beta,
    floatx4* __restrict__ y4)
{
    const long long base = (long long)blockIdx.x * 512 + threadIdx.x;

    #pragma unroll
    for (int k = 0; k < 2; ++k) {
        const long long j = base + k * 256;
        const int c = (int)((j >> C_SHIFT4) & C_MASK);
        const float g = gamma[c];
        const float b = beta[c];

        floatx4 v = x4[j];
        v.x = fmaf(v.x, g, b);
        v.y = fmaf(v.y, g, b);
        v.z = fmaf(v.z, g, b);
        v.w = fmaf(v.w, g, b);
        y4[j] = v;
    }
}

extern "C" void kernel_launch(void* const* d_in, const int* in_sizes, int n_in,
                              void* d_out, int out_size, void* d_ws, size_t ws_size,
                              hipStream_t stream) {
    const float* x     = (const float*)d_in[0];
    const float* gamma = (const float*)d_in[1];
    const float* beta  = (const float*)d_in[2];
    float* y           = (float*)d_out;

    const long long n  = (long long)out_size;   // 67108864 floats
    const long long n4 = n >> 2;                // 16777216 float4s
    const long long grid = n4 / 512;            // 32768 blocks, exact cover

    scale_kernel<<<dim3((unsigned)grid), dim3(256), 0, stream>>>(
        (const floatx4*)x, gamma, beta, (floatx4*)y);
}